// Round 1
// baseline (612.269 us; speedup 1.0000x reference)
//
#include <hip/hip_runtime.h>

#define T_STEPS 512
#define HID 64

typedef short bf16x8 __attribute__((ext_vector_type(8)));
typedef float f32x4 __attribute__((ext_vector_type(4)));

__device__ __forceinline__ float sigm(float x) {
  return __builtin_amdgcn_rcpf(1.f + __expf(-x));
}
__device__ __forceinline__ float tanh_fast(float x) {
  return 1.f - 2.f * __builtin_amdgcn_rcpf(__expf(2.f * x) + 1.f);
}

// split fp32 -> bf16 hi (chop) + bf16 lo (chop of exact residual)
__device__ __forceinline__ void split1(float v, short* hi, short* lo) {
  unsigned u = __float_as_uint(v);
  float r = v - __uint_as_float(u & 0xffff0000u);   // exact in fp32
  *hi = (short)(u >> 16);
  *lo = (short)(__float_as_uint(r) >> 16);
}

__device__ __forceinline__ void split8(const float* __restrict__ p, bf16x8& hi, bf16x8& lo) {
  float v[8];
  *(float4*)&v[0] = *(const float4*)p;
  *(float4*)&v[4] = *(const float4*)(p + 4);
  #pragma unroll
  for (int i = 0; i < 8; ++i) {
    unsigned u = __float_as_uint(v[i]);
    float r = v[i] - __uint_as_float(u & 0xffff0000u);
    hi[i] = (short)(u >> 16);
    lo[i] = (short)(__float_as_uint(r) >> 16);
  }
}

#define MM(acc, A, B) acc = __builtin_amdgcn_mfma_f32_16x16x32_bf16((A), (B), (acc), 0, 0, 0)

// depth-3 chains per K-chunk: Wh*vh + Wh*vl + Wl*vh  (drop Wl*vl, as verified)
#define G3C0(acc, VH0, VL0, NM) do { \
    MM(acc, VH0, NM##h0); MM(acc, VL0, NM##h0); MM(acc, VH0, NM##l0); } while (0)
#define G3C1(acc, VH1, VL1, NM) do { \
    MM(acc, VH1, NM##h1); MM(acc, VL1, NM##h1); MM(acc, VH1, NM##l1); } while (0)

#define WFRAG(NM, Wp, goff) \
  bf16x8 NM##h0, NM##l0, NM##h1, NM##l1; \
  split8((Wp) + (goff) * (64 * HID) + wrowoff, NM##h0, NM##l0); \
  split8((Wp) + (goff) * (64 * HID) + wrowoff + 32, NM##h1, NM##l1)

// LDS A-matrices: logical [m(16)][k(64)] bf16, stored XOR-swizzled in 16B units:
// element idx (shorts) = m*64 + (((k>>3) ^ (m&7))<<3) + (k&7).
// Fragment read (chunk c, lane (nloc,quad)): base = nloc*64 + (((c*4+quad)^(nloc&7))<<3)
// -> conflict-free b128. Batches live at rows m = 4*b; other rows stay zero forever.
//
// R6 restructure: layer 1 runs ONE STEP BEHIND layer 0, so each iteration reads
// only data written before the single trailing barrier. Ping-pong buffers kill
// the WAR hazard that forced the second barrier. Gate accumulations are split
// into 24 independent depth-3 MFMA chains (was 8 chains up to depth 12).
__global__ __launch_bounds__(256, 1) void gru_mfma(
    const float* __restrict__ x,
    const float* __restrict__ Wih0, const float* __restrict__ Whh0,
    const float* __restrict__ bih0, const float* __restrict__ bhh0,
    const float* __restrict__ Wih1, const float* __restrict__ Whh1,
    const float* __restrict__ bih1, const float* __restrict__ bhh1,
    const float* __restrict__ W1, const float* __restrict__ b1,
    const float* __restrict__ W2, const float* __restrict__ b2,
    float* __restrict__ out)
{
  const int tid  = threadIdx.x;
  const int lane = tid & 63;
  const int wv   = tid >> 6;
  const int nloc = lane & 15;
  const int quad = lane >> 4;
  const int b0   = blockIdx.x << 2;

  __shared__ __align__(16) short xsH[2][1024], xsL[2][1024];
  __shared__ __align__(16) short hAH[2][1024], hAL[2][1024];
  __shared__ __align__(16) short hBH[2][1024], hBL[2][1024];
  __shared__ float hfin[256];
  __shared__ float msf[128];

  // ---- weight B-fragments (verified layout, unchanged) ----
  const int wrowoff = (16 * wv + nloc) * HID + 8 * quad;
  WFRAG(i0r, Wih0, 0); WFRAG(i0z, Wih0, 1); WFRAG(i0n, Wih0, 2);
  WFRAG(h0r, Whh0, 0); WFRAG(h0z, Whh0, 1); WFRAG(h0n, Whh0, 2);
  WFRAG(i1r, Wih1, 0); WFRAG(i1z, Wih1, 1); WFRAG(i1n, Wih1, 2);
  WFRAG(h1r, Whh1, 0); WFRAG(h1z, Whh1, 1); WFRAG(h1n, Whh1, 2);

  const int jg = 16 * wv + nloc;
  const float bA_r = bih0[jg] + bhh0[jg];
  const float bA_z = bih0[jg + 64] + bhh0[jg + 64];
  const float bA_i = bih0[jg + 128], bA_h = bhh0[jg + 128];
  const float bB_r = bih1[jg] + bhh1[jg];
  const float bB_z = bih1[jg + 64] + bhh1[jg + 64];
  const float bB_i = bih1[jg + 128], bB_h = bhh1[jg + 128];

  // loop-invariant LDS indices (shorts)
  const int ra0 = nloc * 64 + (((quad    ) ^ (nloc & 7)) << 3);
  const int ra1 = nloc * 64 + (((quad + 4) ^ (nloc & 7)) << 3);
  const int hwr = quad * 256 + (((jg >> 3) ^ ((quad & 1) << 2)) << 3) + (jg & 7);
  const int xwr = wv * 256 + (((lane >> 3) ^ ((wv & 1) << 2)) << 3) + (lane & 7);

  const float* xptr = x + ((size_t)(b0 + wv) * HID + lane) * T_STEPS;
  float xfirst = xptr[0];

  for (int i = tid; i < 1024; i += 256) {
    xsH[0][i] = 0; xsL[0][i] = 0; hAH[0][i] = 0; hAL[0][i] = 0; hBH[0][i] = 0; hBL[0][i] = 0;
    xsH[1][i] = 0; xsL[1][i] = 0; hAH[1][i] = 0; hAL[1][i] = 0; hBH[1][i] = 0; hBL[1][i] = 0;
  }
  __syncthreads();
  // iter 0 reads buffer 1: seed x(0) there (hA(-1)=hB(-2)=0 already)
  { short h, l; split1(xfirst, &h, &l); xsH[1][xwr] = h; xsL[1][xwr] = l; }
  __syncthreads();

  float hpa = 0.f, hpb = 0.f;   // lane's h[batch=quad][j=jg]; hpb lags one step

  #pragma unroll 1
  for (int t = 0; t < T_STEPS; ++t) {
    const int rb = (t & 1) ^ 1;   // read buffer (written during iter t-1)
    const int wb = t & 1;         // write buffer
    float xnext = (t < T_STEPS - 1) ? xptr[t + 1] : 0.f;

    // ---- one read block per step: A = hA(t-1), B = hB(t-2), X = x(t) ----
    bf16x8 AH0 = *(const bf16x8*)&hAH[rb][ra0], AH1 = *(const bf16x8*)&hAH[rb][ra1];
    bf16x8 AL0 = *(const bf16x8*)&hAL[rb][ra0], AL1 = *(const bf16x8*)&hAL[rb][ra1];
    bf16x8 BH0 = *(const bf16x8*)&hBH[rb][ra0], BH1 = *(const bf16x8*)&hBH[rb][ra1];
    bf16x8 BL0 = *(const bf16x8*)&hBL[rb][ra0], BL1 = *(const bf16x8*)&hBL[rb][ra1];
    bf16x8 XH0 = *(const bf16x8*)&xsH[rb][ra0], XH1 = *(const bf16x8*)&xsH[rb][ra1];
    bf16x8 XL0 = *(const bf16x8*)&xsL[rb][ra0], XL1 = *(const bf16x8*)&xsL[rb][ra1];

    const f32x4 z4 = {0.f, 0.f, 0.f, 0.f};

    // ---- layer 0, step t: 12 independent depth-3 chains ----
    f32x4 aRh0 = z4, aRh1 = z4, aRx0 = z4, aRx1 = z4;
    f32x4 aZh0 = z4, aZh1 = z4, aZx0 = z4, aZx1 = z4;
    f32x4 aH0  = z4, aH1  = z4, aI0  = z4, aI1  = z4;
    G3C0(aRh0, AH0, AL0, h0r); G3C1(aRh1, AH1, AL1, h0r);
    G3C0(aH0,  AH0, AL0, h0n); G3C1(aH1,  AH1, AL1, h0n);
    G3C0(aRx0, XH0, XL0, i0r); G3C1(aRx1, XH1, XL1, i0r);
    G3C0(aI0,  XH0, XL0, i0n); G3C1(aI1,  XH1, XL1, i0n);
    G3C0(aZh0, AH0, AL0, h0z); G3C1(aZh1, AH1, AL1, h0z);
    G3C0(aZx0, XH0, XL0, i0z); G3C1(aZx1, XH1, XL1, i0z);

    // ---- layer 1, step t-1: 12 independent depth-3 chains ----
    f32x4 cRh0 = z4, cRh1 = z4, cRx0 = z4, cRx1 = z4;
    f32x4 cZh0 = z4, cZh1 = z4, cZx0 = z4, cZx1 = z4;
    f32x4 cH0  = z4, cH1  = z4, cI0  = z4, cI1  = z4;
    G3C0(cRh0, BH0, BL0, h1r); G3C1(cRh1, BH1, BL1, h1r);
    G3C0(cH0,  BH0, BL0, h1n); G3C1(cH1,  BH1, BL1, h1n);
    G3C0(cRx0, AH0, AL0, i1r); G3C1(cRx1, AH1, AL1, i1r);
    G3C0(cI0,  AH0, AL0, i1n); G3C1(cI1,  AH1, AL1, i1n);
    G3C0(cZh0, BH0, BL0, h1z); G3C1(cZh1, BH1, BL1, h1z);
    G3C0(cZx0, AH0, AL0, i1z); G3C1(cZx1, AH1, AL1, i1z);

    // ---- layer 0 gate math -> hA(t) ----
    {
      float r = sigm((aRx0[0] + aRx1[0]) + (aRh0[0] + aRh1[0]) + bA_r);
      float z = sigm((aZx0[0] + aZx1[0]) + (aZh0[0] + aZh1[0]) + bA_z);
      float n = tanh_fast(((aI0[0] + aI1[0]) + bA_i) + r * ((aH0[0] + aH1[0]) + bA_h));
      hpa = n + z * (hpa - n);
      short h, l; split1(hpa, &h, &l);
      hAH[wb][hwr] = h; hAL[wb][hwr] = l;
    }
    // ---- layer 1 gate math -> hB(t-1); t==0 writes zeros (== hB(-1)) ----
    {
      float r = sigm((cRx0[0] + cRx1[0]) + (cRh0[0] + cRh1[0]) + bB_r);
      float z = sigm((cZx0[0] + cZx1[0]) + (cZh0[0] + cZh1[0]) + bB_z);
      float n = tanh_fast(((cI0[0] + cI1[0]) + bB_i) + r * ((cH0[0] + cH1[0]) + bB_h));
      hpb = (t > 0) ? (n + z * (hpb - n)) : 0.f;
      short h, l; split1(hpb, &h, &l);
      hBH[wb][hwr] = h; hBL[wb][hwr] = l;
    }
    { short h, l; split1(xnext, &h, &l); xsH[wb][xwr] = h; xsL[wb][xwr] = l; }
    __syncthreads();                       // single barrier per step
  }

  // ---- epilogue: layer 1, step T-1 (reads buffer written at iter T-1) ----
  {
    const int rb = (T_STEPS - 1) & 1;      // == 1
    bf16x8 AH0 = *(const bf16x8*)&hAH[rb][ra0], AH1 = *(const bf16x8*)&hAH[rb][ra1];
    bf16x8 AL0 = *(const bf16x8*)&hAL[rb][ra0], AL1 = *(const bf16x8*)&hAL[rb][ra1];
    bf16x8 BH0 = *(const bf16x8*)&hBH[rb][ra0], BH1 = *(const bf16x8*)&hBH[rb][ra1];
    bf16x8 BL0 = *(const bf16x8*)&hBL[rb][ra0], BL1 = *(const bf16x8*)&hBL[rb][ra1];

    const f32x4 z4 = {0.f, 0.f, 0.f, 0.f};
    f32x4 cRh0 = z4, cRh1 = z4, cRx0 = z4, cRx1 = z4;
    f32x4 cZh0 = z4, cZh1 = z4, cZx0 = z4, cZx1 = z4;
    f32x4 cH0  = z4, cH1  = z4, cI0  = z4, cI1  = z4;
    G3C0(cRh0, BH0, BL0, h1r); G3C1(cRh1, BH1, BL1, h1r);
    G3C0(cH0,  BH0, BL0, h1n); G3C1(cH1,  BH1, BL1, h1n);
    G3C0(cRx0, AH0, AL0, i1r); G3C1(cRx1, AH1, AL1, i1r);
    G3C0(cI0,  AH0, AL0, i1n); G3C1(cI1,  AH1, AL1, i1n);
    G3C0(cZh0, BH0, BL0, h1z); G3C1(cZh1, BH1, BL1, h1z);
    G3C0(cZx0, AH0, AL0, i1z); G3C1(cZx1, AH1, AL1, i1z);

    float r = sigm((cRx0[0] + cRx1[0]) + (cRh0[0] + cRh1[0]) + bB_r);
    float z = sigm((cZx0[0] + cZx1[0]) + (cZh0[0] + cZh1[0]) + bB_z);
    float n = tanh_fast(((cI0[0] + cI1[0]) + bB_i) + r * ((cH0[0] + cH1[0]) + bB_h));
    hpb = n + z * (hpb - n);
    hfin[quad * 64 + jg] = hpb;
  }
  __syncthreads();

  // ---- classifier on hfin = hB(T-1), fp32 ----
  if (tid < 128) {
    const int bb = tid >> 5, u = tid & 31;
    float acc = b1[u];
    const float* w1r = W1 + u * HID;
    #pragma unroll
    for (int k = 0; k < 64; ++k)
      acc = fmaf(w1r[k], hfin[bb * 64 + k], acc);
    msf[(bb << 5) + u] = fmaxf(acc, 0.f);
  }
  __syncthreads();
  if (tid < 16) {
    const int bb = tid >> 2, c = tid & 3;
    float acc = b2[c];
    const float* w2r = W2 + (c << 5);
    #pragma unroll
    for (int u = 0; u < 32; ++u)
      acc = fmaf(w2r[u], msf[(bb << 5) + u], acc);
    out[(size_t)(b0 + bb) * 4 + c] = acc;
  }
}

extern "C" void kernel_launch(void* const* d_in, const int* in_sizes, int n_in,
                              void* d_out, int out_size, void* d_ws, size_t ws_size,
                              hipStream_t stream) {
  const float* x    = (const float*)d_in[0];
  const float* Wih0 = (const float*)d_in[1];
  const float* Whh0 = (const float*)d_in[2];
  const float* bih0 = (const float*)d_in[3];
  const float* bhh0 = (const float*)d_in[4];
  const float* Wih1 = (const float*)d_in[5];
  const float* Whh1 = (const float*)d_in[6];
  const float* bih1 = (const float*)d_in[7];
  const float* bhh1 = (const float*)d_in[8];
  const float* W1   = (const float*)d_in[9];
  const float* b1   = (const float*)d_in[10];
  const float* W2   = (const float*)d_in[11];
  const float* b2   = (const float*)d_in[12];
  float* out = (float*)d_out;

  hipLaunchKernelGGL(gru_mfma, dim3(256), dim3(256), 0, stream,
                     x, Wih0, Whh0, bih0, bhh0, Wih1, Whh1, bih1, bhh1,
                     W1, b1, W2, b2, out);
}